// Round 5
// baseline (466.266 us; speedup 1.0000x reference)
//
#include <hip/hip_runtime.h>
#include <math.h>

#define BB 2
#define TT 1024
#define DD 1536
#define HH 12
#define TQK 768
#define TVv 1536
#define CQKV 3072
#define EPSF 1e-6f
#define TSC 64   // scan time-tile

typedef __attribute__((ext_vector_type(8))) short short8v;
typedef __attribute__((ext_vector_type(4))) float f32x4;

__device__ __forceinline__ float siluf(float x) { return x / (1.f + expf(-x)); }

__device__ __forceinline__ ushort f2b(float f) {
  union { float f; uint u; } a; a.f = f;
  uint u = a.u;
  uint r = (u + 0x7fffu + ((u >> 16) & 1u)) >> 16;   // round-to-nearest-even
  return (ushort)r;
}
__device__ __forceinline__ float b2f(ushort h) {
  union { uint u; float f; } a; a.u = (uint)h << 16; return a.f;
}

// DPP add: x += lane-permuted x. Pure VALU (no DS pipe).
// 0xB1=quad_perm[1,0,3,2] (xor1), 0x4E=quad_perm[2,3,0,1] (xor2),
// 0x141=row_half_mirror (pairs 4-groups within 8), 0x140=row_mirror (pairs
// 8-groups within 16). All permutations stay inside a 16-lane row.
template <int CTRL>
__device__ __forceinline__ float dpp_xadd(float x) {
  union { float f; int i; } a, b;
  a.f = x;
  b.i = __builtin_amdgcn_update_dpp(0, a.i, CTRL, 0xF, 0xF, true);
  return x + b.f;
}
__device__ __forceinline__ float red16_dpp(float x) {
  x = dpp_xadd<0xB1>(x);
  x = dpp_xadd<0x4E>(x);
  x = dpp_xadd<0x141>(x);
  x = dpp_xadd<0x140>(x);
  return x;
}

// ---------------------------------------------------------------------------
// Split-bf16 MFMA GEMM: C = X @ W^T with X ~ Xh+Xl, W ~ Wh+Wl (bf16 pairs).
// acc += Xl*Wh + Xh*Wl + Xh*Wh. 128x128 tile, BK=64, 4 waves, 4x4 frags of
// mfma_f32_16x16x32_bf16. LDS row stride 72 ushorts.
// ---------------------------------------------------------------------------
__global__ __launch_bounds__(256) void gemm_bf16s(
    const ushort* __restrict__ Xh, const ushort* __restrict__ Xl,
    const ushort* __restrict__ Wh, const ushort* __restrict__ Wl,
    float* __restrict__ C, int M, int N, int K, int ldc)
{
  __shared__ ushort Ah[128 * 72];
  __shared__ ushort Al[128 * 72];
  __shared__ ushort Bh[128 * 72];
  __shared__ ushort Bl[128 * 72];
  const int tid  = threadIdx.x;
  const int lane = tid & 63;
  const int wid  = tid >> 6;
  const int wr   = wid >> 1, wc = wid & 1;
  const int r0   = blockIdx.y * 128, c0 = blockIdx.x * 128;

  f32x4 acc[4][4];
#pragma unroll
  for (int m = 0; m < 4; ++m)
#pragma unroll
    for (int n = 0; n < 4; ++n)
#pragma unroll
      for (int j = 0; j < 4; ++j) acc[m][n][j] = 0.f;

  for (int k0 = 0; k0 < K; k0 += 64) {
#pragma unroll
    for (int p = 0; p < 4; ++p) {
      int id  = tid + p * 256;
      int row = id >> 3;
      int kc8 = id & 7;
      size_t xo = (size_t)(r0 + row) * K + k0 + kc8 * 8;
      size_t wo = (size_t)(c0 + row) * K + k0 + kc8 * 8;
      *(f32x4*)(Ah + row * 72 + kc8 * 8) = *(const f32x4*)(Xh + xo);
      *(f32x4*)(Al + row * 72 + kc8 * 8) = *(const f32x4*)(Xl + xo);
      *(f32x4*)(Bh + row * 72 + kc8 * 8) = *(const f32x4*)(Wh + wo);
      *(f32x4*)(Bl + row * 72 + kc8 * 8) = *(const f32x4*)(Wl + wo);
    }
    __syncthreads();
#pragma unroll
    for (int kk = 0; kk < 2; ++kk) {
      const int koff = kk * 32 + (lane >> 4) * 8;
      short8v ah[4], al_[4], bh[4], bl[4];
#pragma unroll
      for (int m = 0; m < 4; ++m) {
        const int ro = (wr * 64 + m * 16 + (lane & 15)) * 72 + koff;
        ah[m]  = *(const short8v*)(Ah + ro);
        al_[m] = *(const short8v*)(Al + ro);
      }
#pragma unroll
      for (int n = 0; n < 4; ++n) {
        const int ro = (wc * 64 + n * 16 + (lane & 15)) * 72 + koff;
        bh[n] = *(const short8v*)(Bh + ro);
        bl[n] = *(const short8v*)(Bl + ro);
      }
#pragma unroll
      for (int m = 0; m < 4; ++m)
#pragma unroll
        for (int n = 0; n < 4; ++n) {
          acc[m][n] = __builtin_amdgcn_mfma_f32_16x16x32_bf16(al_[m], bh[n], acc[m][n], 0, 0, 0);
          acc[m][n] = __builtin_amdgcn_mfma_f32_16x16x32_bf16(ah[m], bl[n], acc[m][n], 0, 0, 0);
          acc[m][n] = __builtin_amdgcn_mfma_f32_16x16x32_bf16(ah[m], bh[n], acc[m][n], 0, 0, 0);
        }
    }
    __syncthreads();
  }

  const int crow = (lane >> 4) * 4;
  const int ccol = lane & 15;
#pragma unroll
  for (int m = 0; m < 4; ++m)
#pragma unroll
    for (int j = 0; j < 4; ++j) {
      float* cp = C + (size_t)(r0 + wr * 64 + m * 16 + crow + j) * ldc + c0 + wc * 64 + ccol;
#pragma unroll
      for (int n = 0; n < 4; ++n) cp[n * 16] = acc[m][n][j];
    }
}

// ---------------------------------------------------------------------------
// f32 -> (bf16 hi, bf16 lo) split cast, 8 elems/thread, exact grid.
// ---------------------------------------------------------------------------
__device__ __forceinline__ void split8_store(const float* f, ushort* hi, ushort* lo, size_t e)
{
  ushort h[8], l[8];
#pragma unroll
  for (int j = 0; j < 8; ++j) {
    h[j] = f2b(f[j]);
    l[j] = f2b(f[j] - b2f(h[j]));
  }
  uint4 ph, pl;
  ph.x = (uint)h[0] | ((uint)h[1] << 16); ph.y = (uint)h[2] | ((uint)h[3] << 16);
  ph.z = (uint)h[4] | ((uint)h[5] << 16); ph.w = (uint)h[6] | ((uint)h[7] << 16);
  pl.x = (uint)l[0] | ((uint)l[1] << 16); pl.y = (uint)l[2] | ((uint)l[3] << 16);
  pl.z = (uint)l[4] | ((uint)l[5] << 16); pl.w = (uint)l[6] | ((uint)l[7] << 16);
  *(uint4*)(hi + e) = ph;
  *(uint4*)(lo + e) = pl;
}

__global__ void cast_pair_kernel(const float* __restrict__ src,
                                 ushort* __restrict__ hi, ushort* __restrict__ lo)
{
  int cid = blockIdx.x * blockDim.x + threadIdx.x;
  size_t e = (size_t)cid * 8;
  float f[8];
  *(float4*)(f)     = *(const float4*)(src + e);
  *(float4*)(f + 4) = *(const float4*)(src + e + 4);
  split8_store(f, hi, lo, e);
}

// Concatenated q|k|v weight cast into (3072,1536) hi/lo.
__global__ void cast_qkv_kernel(const float* __restrict__ wq, const float* __restrict__ wk,
                                const float* __restrict__ wv,
                                ushort* __restrict__ hi, ushort* __restrict__ lo)
{
  int cid = blockIdx.x * blockDim.x + threadIdx.x;
  size_t e = (size_t)cid * 8;
  const float* src; size_t off;
  if (e < 1179648)      { src = wq; off = e; }
  else if (e < 2359296) { src = wk; off = e - 1179648; }
  else                  { src = wv; off = e - 2359296; }
  float f[8];
  *(float4*)(f)     = *(const float4*)(src + off);
  *(float4*)(f + 4) = *(const float4*)(src + off + 4);
  split8_store(f, hi, lo, e);
}

// ---------------------------------------------------------------------------
// Causal depthwise conv (K=4) + SiLU; writes q/k/v transposed to (B,H,T,D).
// ---------------------------------------------------------------------------
__global__ void conv_silu_kernel(
    const float* __restrict__ pre,
    const float* __restrict__ qw, const float* __restrict__ kw, const float* __restrict__ vw,
    float* __restrict__ qc, float* __restrict__ kc, float* __restrict__ vc)
{
  int idx = blockIdx.x * blockDim.x + threadIdx.x;
  if (idx >= BB * TT * CQKV) return;
  int c  = idx % CQKV;
  int bt = idx / CQKV;
  int t  = bt % TT;
  int b  = bt / TT;

  const float* wp;
  if (c < TQK)          wp = qw + (size_t)c * 4;
  else if (c < 2 * TQK) wp = kw + (size_t)(c - TQK) * 4;
  else                  wp = vw + (size_t)(c - 2 * TQK) * 4;

  float s = 0.f;
#pragma unroll
  for (int j = 0; j < 4; ++j) {
    int ts = t - 3 + j;
    if (ts >= 0) s = fmaf(pre[(size_t)(b * TT + ts) * CQKV + c], wp[j], s);
  }
  s = siluf(s);

  if (c < TQK) {
    int h = c >> 6, d = c & 63;
    qc[((size_t)(b * HH + h) * TT + t) * 64 + d] = s;
  } else if (c < 2 * TQK) {
    int c2 = c - TQK; int h = c2 >> 6, d = c2 & 63;
    kc[((size_t)(b * HH + h) * TT + t) * 64 + d] = s;
  } else {
    int c2 = c - 2 * TQK; int h = c2 >> 7, d = c2 & 127;
    vc[((size_t)(b * HH + h) * TT + t) * 128 + d] = s;
  }
}

__global__ void l2norm64_kernel(float* __restrict__ buf, int nrows)
{
  int gid  = blockIdx.x * blockDim.x + threadIdx.x;
  int row  = gid >> 6;
  int lane = threadIdx.x & 63;
  if (row >= nrows) return;
  float v = buf[(size_t)row * 64 + lane];
  float ss = v * v;
#pragma unroll
  for (int m = 32; m >= 1; m >>= 1) ss += __shfl_xor(ss, m, 64);
  float n = sqrtf(ss);
  buf[(size_t)row * 64 + lane] = v / fmaxf(n, EPSF);
}

// ---------------------------------------------------------------------------
// Gating: one block per row m; 4 waves x 6 outputs (12 a-dots + 12 b-dots).
// ---------------------------------------------------------------------------
__global__ __launch_bounds__(256) void gate_kernel(
    const float* __restrict__ x, const float* __restrict__ w_a, const float* __restrict__ w_b,
    const float* __restrict__ A_log, const float* __restrict__ dt_bias,
    float* __restrict__ alpha, float* __restrict__ beta)
{
  const int m    = blockIdx.x;          // 0..2047
  const int w    = threadIdx.x >> 6;    // 0..3
  const int lane = threadIdx.x & 63;
  const float* xr = x + (size_t)m * DD;
  float xv[24];
#pragma unroll
  for (int i = 0; i < 24; ++i) xv[i] = xr[lane + i * 64];
  const int b = m / TT, t = m % TT;
#pragma unroll
  for (int j = 0; j < 6; ++j) {
    int o = w * 6 + j;                  // 0..23
    bool isA = o < HH;
    int h = isA ? o : o - HH;
    const float* wr = (isA ? w_a : w_b) + (size_t)h * DD;
    float s = 0.f;
#pragma unroll
    for (int i = 0; i < 24; ++i) s = fmaf(xv[i], wr[lane + i * 64], s);
#pragma unroll
    for (int mm = 32; mm >= 1; mm >>= 1) s += __shfl_xor(s, mm, 64);
    if (lane == 0) {
      size_t idx = (size_t)(b * HH + h) * TT + t;
      if (isA) {
        float a  = s + dt_bias[h];
        float sp = (a > 20.f) ? a : log1pf(expf(a));
        alpha[idx] = expf(-expf(A_log[h]) * sp);
      } else {
        beta[idx] = 2.f / (1.f + expf(-s));
      }
    }
  }
}

// ---------------------------------------------------------------------------
// Gated delta scan. 192 blocks = (B*H) x 8 vblocks of 16 columns.
// 256 thr = 16 cols x 16 lanes; each lane owns 4 of the 64 d's.
// k/q: one ds_read_b128 each per step; v: ds_read_b32; alpha/beta: scalar
// (SMEM) loads via wave-uniform index. Reduces: 4 DPP levels (pure VALU).
// ---------------------------------------------------------------------------
__global__ __launch_bounds__(256) void scan_kernel(
    const float* __restrict__ qc, const float* __restrict__ kc, const float* __restrict__ vc,
    const float* __restrict__ alpha, const float* __restrict__ beta,
    float* __restrict__ o)
{
  __shared__ float k_lds[TSC * 64];
  __shared__ float q_lds[TSC * 64];
  __shared__ float v_lds[TSC * 16];

  const int blk  = blockIdx.x;
  const int vblk = blk & 7;           // 0..7
  const int bh   = blk >> 3;          // 0..23
  const int b    = bh / HH, h = bh % HH;
  const int tid  = threadIdx.x;
  const int col  = tid >> 4;          // 0..15
  const int s    = tid & 15;          // 0..15, owns d = s*4..s*4+3
  const int v    = vblk * 16 + col;

  const float* kg = kc + (size_t)bh * TT * 64;
  const float* qg = qc + (size_t)bh * TT * 64;
  const float* vg = vc + (size_t)bh * TT * 128 + vblk * 16;
  const float* ag = alpha + (size_t)bh * TT;
  const float* bg = beta  + (size_t)bh * TT;
  float* op = o + ((size_t)b * TT * HH + h) * 128 + v;

  float S[4];
#pragma unroll
  for (int i = 0; i < 4; ++i) S[i] = 0.f;

  float4 rk[4], rq[4], rv;
#define LOADTILE(T0) do { \
    _Pragma("unroll") \
    for (int c = 0; c < 4; ++c) { \
      rk[c] = *(const float4*)(kg + (size_t)(T0) * 64 + c * 1024 + tid * 4); \
      rq[c] = *(const float4*)(qg + (size_t)(T0) * 64 + c * 1024 + tid * 4); \
    } \
    rv = *(const float4*)(vg + (size_t)((T0) + (tid >> 2)) * 128 + (tid & 3) * 4); \
  } while (0)

  LOADTILE(0);
  for (int tile = 0; tile < TT / TSC; ++tile) {
    __syncthreads();                       // prior tile's reads complete
#pragma unroll
    for (int c = 0; c < 4; ++c) {
      *(float4*)(k_lds + c * 1024 + tid * 4) = rk[c];
      *(float4*)(q_lds + c * 1024 + tid * 4) = rq[c];
    }
    *(float4*)(v_lds + (tid >> 2) * 16 + (tid & 3) * 4) = rv;
    if (tile + 1 < TT / TSC) LOADTILE((tile + 1) * TSC);  // in flight during compute
    __syncthreads();

    const int t0 = tile * TSC;
#pragma unroll 8
    for (int i = 0; i < TSC; ++i) {
      const float4 kk = *(const float4*)(k_lds + i * 64 + s * 4);
      const float4 qq = *(const float4*)(q_lds + i * 64 + s * 4);
      const float vt = v_lds[i * 16 + col];
      const float al = ag[t0 + i];       // wave-uniform -> s_load (SMEM pipe)
      const float be = bg[t0 + i];

      float pa = fmaf(kk.y, S[1], kk.x * S[0]);
      float pb = fmaf(kk.w, S[3], kk.z * S[2]);
      float sa = fmaf(qq.y, S[1], qq.x * S[0]);
      float sb = fmaf(qq.w, S[3], qq.z * S[2]);
      float ta = fmaf(qq.y, kk.y, qq.x * kk.x);
      float tb = fmaf(qq.w, kk.w, qq.z * kk.z);

      float part = red16_dpp(pa + pb);   // k.S (serial chain, pure VALU)
      float qs   = red16_dpp(sa + sb);   // q.S (off-chain)
      float qk   = red16_dpp(ta + tb);   // q.k (off-chain)
      const float c = fmaf(-al * be, part, vt);
      S[0] = fmaf(al, S[0], c * kk.x);
      S[1] = fmaf(al, S[1], c * kk.y);
      S[2] = fmaf(al, S[2], c * kk.z);
      S[3] = fmaf(al, S[3], c * kk.w);
      if (s == 0) *op = fmaf(al, qs, c * qk);
      op += HH * 128;
    }
  }
#undef LOADTILE
}

// ---------------------------------------------------------------------------
// RMS norm over 128 + SiLU gate; emits split bf16 (hi+lo) for final GEMM.
// ---------------------------------------------------------------------------
__global__ void rmsgate_kernel(const float* __restrict__ o, const float* __restrict__ gpre,
                               ushort* __restrict__ goh, ushort* __restrict__ gol)
{
  int gid  = blockIdx.x * blockDim.x + threadIdx.x;
  int wid  = gid >> 6;
  int lane = threadIdx.x & 63;
  if (wid >= BB * TT * HH) return;
  int h = wid % HH;
  int m = wid / HH;
  const float* orow = o + (size_t)wid * 128;
  float2 ov = *(const float2*)(orow + lane * 2);
  float ss = ov.x * ov.x + ov.y * ov.y;
#pragma unroll
  for (int mm = 32; mm >= 1; mm >>= 1) ss += __shfl_xor(ss, mm, 64);
  float scale = rsqrtf(ss * (1.f / 128.f) + EPSF);
  const float* gr = gpre + (size_t)m * TVv + h * 128 + lane * 2;
  float o0 = ov.x * scale * siluf(gr[0]);
  float o1 = ov.y * scale * siluf(gr[1]);
  ushort h0 = f2b(o0), h1 = f2b(o1);
  ushort l0 = f2b(o0 - b2f(h0)), l1 = f2b(o1 - b2f(h1));
  size_t idx = (size_t)m * TVv + h * 128 + lane * 2;
  *(uint*)(goh + idx) = (uint)h0 | ((uint)h1 << 16);
  *(uint*)(gol + idx) = (uint)l0 | ((uint)l1 << 16);
}

// ---------------------------------------------------------------------------
extern "C" void kernel_launch(void* const* d_in, const int* in_sizes, int n_in,
                              void* d_out, int out_size, void* d_ws, size_t ws_size,
                              hipStream_t stream) {
  (void)in_sizes; (void)n_in; (void)out_size; (void)ws_size;
  const float* x       = (const float*)d_in[0];
  const float* w_q     = (const float*)d_in[1];
  const float* w_k     = (const float*)d_in[2];
  const float* w_v     = (const float*)d_in[3];
  const float* w_a     = (const float*)d_in[4];
  const float* w_b     = (const float*)d_in[5];
  const float* w_g     = (const float*)d_in[6];
  const float* w_out   = (const float*)d_in[7];
  const float* A_log   = (const float*)d_in[8];
  const float* dt_bias = (const float*)d_in[9];
  const float* qcw     = (const float*)d_in[10];
  const float* kcw     = (const float*)d_in[11];
  const float* vcw     = (const float*)d_in[12];

  // Workspace (63.11 MB, same proven footprint):
  //  qkv_pre [0 .. 6291456)      f32; later o[0..3145728) + goh/gol
  //  g_pre   [6291456 .. 9437184) f32; transiently holds wcat_hi before g GEMM
  //  Cu      [9437184 .. 15728640): phase1 xh,xl + wcat_lo / wg hi,lo
  //                                 phase2 qc,kc,vc ; phase3 wout hi,lo
  //  alpha/beta [15728640 .. 15777792)
  float* ws      = (float*)d_ws;
  float* qkv_pre = ws;
  float* g_pre   = ws + 6291456;
  float* Cu      = ws + 9437184;
  float* alphab  = ws + 15728640;
  float* betab   = ws + 15753216;

  ushort* xh    = (ushort*)Cu;                  // 3,145,728 ushorts
  ushort* xl    = (ushort*)(Cu + 1572864);
  ushort* wcath = (ushort*)g_pre;               // 4,718,592 ushorts (transient)
  ushort* wcatl = (ushort*)(Cu + 3145728);      // 4,718,592 ushorts
  ushort* wgh   = (ushort*)(Cu + 3145728);      // reuses wcatl space after qkv GEMM
  ushort* wgl   = (ushort*)(Cu + 4325376);

  float* qc = Cu;
  float* kc = Cu + 1572864;
  float* vc = Cu + 3145728;

  ushort* wouth = (ushort*)Cu;
  ushort* woutl = (ushort*)(Cu + 1179648);

  float*  o   = qkv_pre;
  ushort* goh = (ushort*)(qkv_pre + 3145728);
  ushort* gol = (ushort*)(qkv_pre + 4718592);

  const int M = BB * TT;  // 2048
  dim3 blk(256);

  // 1) split-casts: x, concatenated q|k|v weights
  cast_pair_kernel<<<1536, blk, 0, stream>>>(x, xh, xl);
  cast_qkv_kernel<<<2304, blk, 0, stream>>>(w_q, w_k, w_v, wcath, wcatl);

  // 2) fused qkv projection (N=3072)
  gemm_bf16s<<<dim3(CQKV / 128, M / 128), blk, 0, stream>>>(xh, xl, wcath, wcatl, qkv_pre, M, CQKV, DD, CQKV);

  // 3) g projection (wcat dead; wg overwrites wcatl, g_pre overwrites wcath)
  cast_pair_kernel<<<1152, blk, 0, stream>>>(w_g, wgh, wgl);
  gemm_bf16s<<<dim3(TVv / 128, M / 128), blk, 0, stream>>>(xh, xl, wgh, wgl, g_pre, M, TVv, DD, TVv);

  // 4) gating coefficients (f32, exact)
  gate_kernel<<<M, blk, 0, stream>>>(x, w_a, w_b, A_log, dt_bias, alphab, betab);

  // 5) causal depthwise conv + SiLU (overwrites Cu with qc/kc/vc)
  conv_silu_kernel<<<(BB * TT * CQKV + 255) / 256, blk, 0, stream>>>(qkv_pre, qcw, kcw, vcw, qc, kc, vc);

  // 6) L2 normalize q,k
  l2norm64_kernel<<<6144, blk, 0, stream>>>(qc, BB * HH * TT);
  l2norm64_kernel<<<6144, blk, 0, stream>>>(kc, BB * HH * TT);

  // 7) scan (16-lane groups, DPP reduces, SMEM alpha/beta)
  scan_kernel<<<BB * HH * 8, blk, 0, stream>>>(qc, kc, vc, alphab, betab, o);

  // 8) split-cast w_out into freed qc/kc space
  cast_pair_kernel<<<1152, blk, 0, stream>>>(w_out, wouth, woutl);

  // 9) RMS norm + SiLU gate -> split bf16
  rmsgate_kernel<<<6144, blk, 0, stream>>>(o, g_pre, goh, gol);

  // 10) output projection
  gemm_bf16s<<<dim3(TVv / 128, M / 128), blk, 0, stream>>>(goh, gol, wouth, woutl, (float*)d_out, M, TVv, DD, TVv);
}

// Round 6
// 449.481 us; speedup vs baseline: 1.0373x; 1.0373x over previous
//
#include <hip/hip_runtime.h>
#include <math.h>

#define BB 2
#define TT 1024
#define DD 1536
#define HH 12
#define TQK 768
#define TVv 1536
#define CQKV 3072
#define EPSF 1e-6f
#define TSC 64   // scan time-tile

typedef __attribute__((ext_vector_type(8))) short short8v;
typedef __attribute__((ext_vector_type(4))) float f32x4;

__device__ __forceinline__ float siluf(float x) { return x / (1.f + expf(-x)); }

__device__ __forceinline__ ushort f2b(float f) {
  union { float f; uint u; } a; a.f = f;
  uint u = a.u;
  uint r = (u + 0x7fffu + ((u >> 16) & 1u)) >> 16;   // round-to-nearest-even
  return (ushort)r;
}
__device__ __forceinline__ float b2f(ushort h) {
  union { uint u; float f; } a; a.u = (uint)h << 16; return a.f;
}

// async global->LDS, 16B per lane (dest = wave-uniform base + lane*16)
__device__ __forceinline__ void gload16(const ushort* g, ushort* l) {
  __builtin_amdgcn_global_load_lds(
      (const __attribute__((address_space(1))) void*)g,
      (__attribute__((address_space(3))) void*)l, 16, 0, 0);
}

// DPP add: x += lane-permuted x. Pure VALU (no DS pipe).
// 0xB1=quad_perm xor1, 0x4E=quad_perm xor2, 0x141=row_half_mirror,
// 0x140=row_mirror. All stay inside a 16-lane row.
template <int CTRL>
__device__ __forceinline__ float dpp_xadd(float x) {
  union { float f; int i; } a, b;
  a.f = x;
  b.i = __builtin_amdgcn_update_dpp(0, a.i, CTRL, 0xF, 0xF, true);
  return x + b.f;
}
__device__ __forceinline__ float red16_dpp(float x) {
  x = dpp_xadd<0xB1>(x);
  x = dpp_xadd<0x4E>(x);
  x = dpp_xadd<0x141>(x);
  x = dpp_xadd<0x140>(x);
  return x;
}

// ---------------------------------------------------------------------------
// Split-bf16 MFMA GEMM: C = X @ W^T, X ~ Xh+Xl, W ~ Wh+Wl (bf16 pairs).
// acc += Xl*Wh + Xh*Wl + Xh*Wh. 128x128 tile, BK=64, 4 waves, 4x4 frags of
// mfma_f32_16x16x32_bf16. Staging via global_load_lds(16B) into linear-row
// LDS (64 ushorts/row) with T2 XOR swizzle: LDS slot s of row r holds global
// 16B-chunk s^(r&7); fragment reads XOR the same way -> conflict-free.
// ---------------------------------------------------------------------------
__global__ __launch_bounds__(256) void gemm_bf16s(
    const ushort* __restrict__ Xh, const ushort* __restrict__ Xl,
    const ushort* __restrict__ Wh, const ushort* __restrict__ Wl,
    float* __restrict__ C, int M, int N, int K, int ldc)
{
  __shared__ ushort Ah[128 * 64];
  __shared__ ushort Al[128 * 64];
  __shared__ ushort Bh[128 * 64];
  __shared__ ushort Bl[128 * 64];
  const int tid  = threadIdx.x;
  const int lane = tid & 63;
  const int w    = tid >> 6;
  const int wr   = w >> 1, wc = w & 1;
  const int r0   = blockIdx.y * 128, c0 = blockIdx.x * 128;

  // staging geometry: wave w, call j covers rows (w*4+j)*8 .. +7 (1KB chunk)
  const int dr   = lane >> 3;             // row within 8-row chunk
  const int slot = (lane & 7) ^ dr;       // pre-swizzled source 16B-chunk

  f32x4 acc[4][4];
#pragma unroll
  for (int m = 0; m < 4; ++m)
#pragma unroll
    for (int n = 0; n < 4; ++n)
#pragma unroll
      for (int j = 0; j < 4; ++j) acc[m][n][j] = 0.f;

  for (int k0 = 0; k0 < K; k0 += 64) {
#pragma unroll
    for (int j = 0; j < 4; ++j) {
      const int row  = (w * 4 + j) * 8 + dr;
      const size_t xo = (size_t)(r0 + row) * K + k0 + slot * 8;
      const size_t wo = (size_t)(c0 + row) * K + k0 + slot * 8;
      const int ldso = (w * 4 + j) * 512;    // elements (1KB)
      gload16(Xh + xo, Ah + ldso);
      gload16(Xl + xo, Al + ldso);
      gload16(Wh + wo, Bh + ldso);
      gload16(Wl + wo, Bl + ldso);
    }
    __syncthreads();
#pragma unroll
    for (int kk = 0; kk < 2; ++kk) {
      const int kc8 = kk * 4 + (lane >> 4);          // 16B chunk in K-slab
      const int sw  = (kc8 ^ (lane & 7)) << 3;       // swizzled element off
      short8v ah[4], al_[4], bh[4], bl[4];
#pragma unroll
      for (int m = 0; m < 4; ++m) {
        const int ro = (wr * 64 + m * 16 + (lane & 15)) * 64 + sw;
        ah[m]  = *(const short8v*)(Ah + ro);
        al_[m] = *(const short8v*)(Al + ro);
      }
#pragma unroll
      for (int n = 0; n < 4; ++n) {
        const int ro = (wc * 64 + n * 16 + (lane & 15)) * 64 + sw;
        bh[n] = *(const short8v*)(Bh + ro);
        bl[n] = *(const short8v*)(Bl + ro);
      }
#pragma unroll
      for (int m = 0; m < 4; ++m)
#pragma unroll
        for (int n = 0; n < 4; ++n) {
          acc[m][n] = __builtin_amdgcn_mfma_f32_16x16x32_bf16(al_[m], bh[n], acc[m][n], 0, 0, 0);
          acc[m][n] = __builtin_amdgcn_mfma_f32_16x16x32_bf16(ah[m], bl[n], acc[m][n], 0, 0, 0);
          acc[m][n] = __builtin_amdgcn_mfma_f32_16x16x32_bf16(ah[m], bh[n], acc[m][n], 0, 0, 0);
        }
    }
    __syncthreads();
  }

  const int crow = (lane >> 4) * 4;
  const int ccol = lane & 15;
#pragma unroll
  for (int m = 0; m < 4; ++m)
#pragma unroll
    for (int j = 0; j < 4; ++j) {
      float* cp = C + (size_t)(r0 + wr * 64 + m * 16 + crow + j) * ldc + c0 + wc * 64 + ccol;
#pragma unroll
      for (int n = 0; n < 4; ++n) cp[n * 16] = acc[m][n][j];
    }
}

// ---------------------------------------------------------------------------
// f32 -> (bf16 hi, bf16 lo) split cast, 8 elems/thread, exact grid.
// ---------------------------------------------------------------------------
__device__ __forceinline__ void split8_store(const float* f, ushort* hi, ushort* lo, size_t e)
{
  ushort h[8], l[8];
#pragma unroll
  for (int j = 0; j < 8; ++j) {
    h[j] = f2b(f[j]);
    l[j] = f2b(f[j] - b2f(h[j]));
  }
  uint4 ph, pl;
  ph.x = (uint)h[0] | ((uint)h[1] << 16); ph.y = (uint)h[2] | ((uint)h[3] << 16);
  ph.z = (uint)h[4] | ((uint)h[5] << 16); ph.w = (uint)h[6] | ((uint)h[7] << 16);
  pl.x = (uint)l[0] | ((uint)l[1] << 16); pl.y = (uint)l[2] | ((uint)l[3] << 16);
  pl.z = (uint)l[4] | ((uint)l[5] << 16); pl.w = (uint)l[6] | ((uint)l[7] << 16);
  *(uint4*)(hi + e) = ph;
  *(uint4*)(lo + e) = pl;
}

__global__ void cast_pair_kernel(const float* __restrict__ src,
                                 ushort* __restrict__ hi, ushort* __restrict__ lo)
{
  int cid = blockIdx.x * blockDim.x + threadIdx.x;
  size_t e = (size_t)cid * 8;
  float f[8];
  *(float4*)(f)     = *(const float4*)(src + e);
  *(float4*)(f + 4) = *(const float4*)(src + e + 4);
  split8_store(f, hi, lo, e);
}

// Concatenated q|k|v weight cast into (3072,1536) hi/lo.
__global__ void cast_qkv_kernel(const float* __restrict__ wq, const float* __restrict__ wk,
                                const float* __restrict__ wv,
                                ushort* __restrict__ hi, ushort* __restrict__ lo)
{
  int cid = blockIdx.x * blockDim.x + threadIdx.x;
  size_t e = (size_t)cid * 8;
  const float* src; size_t off;
  if (e < 1179648)      { src = wq; off = e; }
  else if (e < 2359296) { src = wk; off = e - 1179648; }
  else                  { src = wv; off = e - 2359296; }
  float f[8];
  *(float4*)(f)     = *(const float4*)(src + off);
  *(float4*)(f + 4) = *(const float4*)(src + off + 4);
  split8_store(f, hi, lo, e);
}

// ---------------------------------------------------------------------------
// Causal depthwise conv (K=4) + SiLU; writes q/k/v transposed to (B,H,T,D).
// ---------------------------------------------------------------------------
__global__ void conv_silu_kernel(
    const float* __restrict__ pre,
    const float* __restrict__ qw, const float* __restrict__ kw, const float* __restrict__ vw,
    float* __restrict__ qc, float* __restrict__ kc, float* __restrict__ vc)
{
  int idx = blockIdx.x * blockDim.x + threadIdx.x;
  if (idx >= BB * TT * CQKV) return;
  int c  = idx % CQKV;
  int bt = idx / CQKV;
  int t  = bt % TT;
  int b  = bt / TT;

  const float* wp;
  if (c < TQK)          wp = qw + (size_t)c * 4;
  else if (c < 2 * TQK) wp = kw + (size_t)(c - TQK) * 4;
  else                  wp = vw + (size_t)(c - 2 * TQK) * 4;

  float s = 0.f;
#pragma unroll
  for (int j = 0; j < 4; ++j) {
    int ts = t - 3 + j;
    if (ts >= 0) s = fmaf(pre[(size_t)(b * TT + ts) * CQKV + c], wp[j], s);
  }
  s = siluf(s);

  if (c < TQK) {
    int h = c >> 6, d = c & 63;
    qc[((size_t)(b * HH + h) * TT + t) * 64 + d] = s;
  } else if (c < 2 * TQK) {
    int c2 = c - TQK; int h = c2 >> 6, d = c2 & 63;
    kc[((size_t)(b * HH + h) * TT + t) * 64 + d] = s;
  } else {
    int c2 = c - 2 * TQK; int h = c2 >> 7, d = c2 & 127;
    vc[((size_t)(b * HH + h) * TT + t) * 128 + d] = s;
  }
}

__global__ void l2norm64_kernel(float* __restrict__ buf, int nrows)
{
  int gid  = blockIdx.x * blockDim.x + threadIdx.x;
  int row  = gid >> 6;
  int lane = threadIdx.x & 63;
  if (row >= nrows) return;
  float v = buf[(size_t)row * 64 + lane];
  float ss = v * v;
#pragma unroll
  for (int m = 32; m >= 1; m >>= 1) ss += __shfl_xor(ss, m, 64);
  float n = sqrtf(ss);
  buf[(size_t)row * 64 + lane] = v / fmaxf(n, EPSF);
}

// ---------------------------------------------------------------------------
// Gating: one block per row m; 4 waves x 6 outputs (12 a-dots + 12 b-dots).
// ---------------------------------------------------------------------------
__global__ __launch_bounds__(256) void gate_kernel(
    const float* __restrict__ x, const float* __restrict__ w_a, const float* __restrict__ w_b,
    const float* __restrict__ A_log, const float* __restrict__ dt_bias,
    float* __restrict__ alpha, float* __restrict__ beta)
{
  const int m    = blockIdx.x;          // 0..2047
  const int w    = threadIdx.x >> 6;    // 0..3
  const int lane = threadIdx.x & 63;
  const float* xr = x + (size_t)m * DD;
  float xv[24];
#pragma unroll
  for (int i = 0; i < 24; ++i) xv[i] = xr[lane + i * 64];
  const int b = m / TT, t = m % TT;
#pragma unroll
  for (int j = 0; j < 6; ++j) {
    int o = w * 6 + j;                  // 0..23
    bool isA = o < HH;
    int h = isA ? o : o - HH;
    const float* wr = (isA ? w_a : w_b) + (size_t)h * DD;
    float s = 0.f;
#pragma unroll
    for (int i = 0; i < 24; ++i) s = fmaf(xv[i], wr[lane + i * 64], s);
#pragma unroll
    for (int mm = 32; mm >= 1; mm >>= 1) s += __shfl_xor(s, mm, 64);
    if (lane == 0) {
      size_t idx = (size_t)(b * HH + h) * TT + t;
      if (isA) {
        float a  = s + dt_bias[h];
        float sp = (a > 20.f) ? a : log1pf(expf(a));
        alpha[idx] = expf(-expf(A_log[h]) * sp);
      } else {
        beta[idx] = 2.f / (1.f + expf(-s));
      }
    }
  }
}

// ---------------------------------------------------------------------------
// Gated delta scan. 96 blocks = (B*H) x 4 vblocks of 32 columns.
// 512 thr = 32 cols x 16 lanes (2 waves/SIMD for stall overlap); each lane
// owns 4 of the 64 d's. Per step per wave: 2x ds_read_b128 (k,q broadcast),
// 1x ds_read_b32 (v), 1x ds_read_b64 (alpha/beta interleaved, broadcast).
// Reduces: 4 DPP levels (pure VALU). Output off the serial chain.
// ---------------------------------------------------------------------------
__global__ __launch_bounds__(512) void scan_kernel(
    const float* __restrict__ qc, const float* __restrict__ kc, const float* __restrict__ vc,
    const float* __restrict__ alpha, const float* __restrict__ beta,
    float* __restrict__ o)
{
  __shared__ float k_lds[TSC * 64];
  __shared__ float q_lds[TSC * 64];
  __shared__ float v_lds[TSC * 32];
  __shared__ float ab_lds[TSC * 2];

  const int blk  = blockIdx.x;
  const int vblk = blk & 3;           // 0..3
  const int bh   = blk >> 2;          // 0..23
  const int b    = bh / HH, h = bh % HH;
  const int tid  = threadIdx.x;       // 0..511
  const int col  = tid >> 4;          // 0..31
  const int s    = tid & 15;          // 0..15, owns d = s*4..s*4+3
  const int v    = vblk * 32 + col;

  const float* kg = kc + (size_t)bh * TT * 64;
  const float* qg = qc + (size_t)bh * TT * 64;
  const float* vg = vc + (size_t)bh * TT * 128 + vblk * 32;
  const float* ag = alpha + (size_t)bh * TT;
  const float* bg = beta  + (size_t)bh * TT;
  float* op = o + ((size_t)b * TT * HH + h) * 128 + v;

  float S[4];
#pragma unroll
  for (int i = 0; i < 4; ++i) S[i] = 0.f;

  float4 rk0, rk1, rq0, rq1, rv; float rab;
#define LOADTILE(T0) do { \
    rk0 = *(const float4*)(kg + (size_t)(T0) * 64 + tid * 4); \
    rk1 = *(const float4*)(kg + (size_t)(T0) * 64 + 2048 + tid * 4); \
    rq0 = *(const float4*)(qg + (size_t)(T0) * 64 + tid * 4); \
    rq1 = *(const float4*)(qg + (size_t)(T0) * 64 + 2048 + tid * 4); \
    rv  = *(const float4*)(vg + (size_t)((T0) + (tid >> 3)) * 128 + (tid & 7) * 4); \
    rab = (tid < 64) ? ag[(T0) + tid] : ((tid < 128) ? bg[(T0) + tid - 64] : 0.f); \
  } while (0)

  LOADTILE(0);
  for (int tile = 0; tile < TT / TSC; ++tile) {
    __syncthreads();                       // prior tile's reads complete
    *(float4*)(k_lds + tid * 4)        = rk0;
    *(float4*)(k_lds + 2048 + tid * 4) = rk1;
    *(float4*)(q_lds + tid * 4)        = rq0;
    *(float4*)(q_lds + 2048 + tid * 4) = rq1;
    *(float4*)(v_lds + (tid >> 3) * 32 + (tid & 7) * 4) = rv;
    if (tid < 64) ab_lds[2 * tid] = rab;
    else if (tid < 128) ab_lds[2 * (tid - 64) + 1] = rab;
    if (tile + 1 < TT / TSC) LOADTILE((tile + 1) * TSC);  // overlap compute
    __syncthreads();

#pragma unroll 8
    for (int i = 0; i < TSC; ++i) {
      const float4 kk = *(const float4*)(k_lds + i * 64 + s * 4);
      const float4 qq = *(const float4*)(q_lds + i * 64 + s * 4);
      const float vt = v_lds[i * 32 + col];
      const float2 ab = *(const float2*)(ab_lds + 2 * i);
      const float al = ab.x, be = ab.y;

      float pa = fmaf(kk.y, S[1], kk.x * S[0]);
      float pb = fmaf(kk.w, S[3], kk.z * S[2]);
      float sa = fmaf(qq.y, S[1], qq.x * S[0]);
      float sb = fmaf(qq.w, S[3], qq.z * S[2]);
      float ta = fmaf(qq.y, kk.y, qq.x * kk.x);
      float tb = fmaf(qq.w, kk.w, qq.z * kk.z);

      float part = red16_dpp(pa + pb);   // k.S (serial chain, pure VALU)
      float qs   = red16_dpp(sa + sb);   // q.S (off-chain)
      float qk   = red16_dpp(ta + tb);   // q.k (off-chain)
      const float c = fmaf(-al * be, part, vt);
      S[0] = fmaf(al, S[0], c * kk.x);
      S[1] = fmaf(al, S[1], c * kk.y);
      S[2] = fmaf(al, S[2], c * kk.z);
      S[3] = fmaf(al, S[3], c * kk.w);
      if (s == 0) *op = fmaf(al, qs, c * qk);
      op += HH * 128;
    }
  }
#undef LOADTILE
}

// ---------------------------------------------------------------------------
// RMS norm over 128 + SiLU gate; emits split bf16 (hi+lo) for final GEMM.
// ---------------------------------------------------------------------------
__global__ void rmsgate_kernel(const float* __restrict__ o, const float* __restrict__ gpre,
                               ushort* __restrict__ goh, ushort* __restrict__ gol)
{
  int gid  = blockIdx.x * blockDim.x + threadIdx.x;
  int wid  = gid >> 6;
  int lane = threadIdx.x & 63;
  if (wid >= BB * TT * HH) return;
  int h = wid % HH;
  int m = wid / HH;
  const float* orow = o + (size_t)wid * 128;
  float2 ov = *(const float2*)(orow + lane * 2);
  float ss = ov.x * ov.x + ov.y * ov.y;
#pragma unroll
  for (int mm = 32; mm >= 1; mm >>= 1) ss += __shfl_xor(ss, mm, 64);
  float scale = rsqrtf(ss * (1.f / 128.f) + EPSF);
  const float* gr = gpre + (size_t)m * TVv + h * 128 + lane * 2;
  float o0 = ov.x * scale * siluf(gr[0]);
  float o1 = ov.y * scale * siluf(gr[1]);
  ushort h0 = f2b(o0), h1 = f2b(o1);
  ushort l0 = f2b(o0 - b2f(h0)), l1 = f2b(o1 - b2f(h1));
  size_t idx = (size_t)m * TVv + h * 128 + lane * 2;
  *(uint*)(goh + idx) = (uint)h0 | ((uint)h1 << 16);
  *(uint*)(gol + idx) = (uint)l0 | ((uint)l1 << 16);
}

// ---------------------------------------------------------------------------
extern "C" void kernel_launch(void* const* d_in, const int* in_sizes, int n_in,
                              void* d_out, int out_size, void* d_ws, size_t ws_size,
                              hipStream_t stream) {
  (void)in_sizes; (void)n_in; (void)out_size; (void)ws_size;
  const float* x       = (const float*)d_in[0];
  const float* w_q     = (const float*)d_in[1];
  const float* w_k     = (const float*)d_in[2];
  const float* w_v     = (const float*)d_in[3];
  const float* w_a     = (const float*)d_in[4];
  const float* w_b     = (const float*)d_in[5];
  const float* w_g     = (const float*)d_in[6];
  const float* w_out   = (const float*)d_in[7];
  const float* A_log   = (const float*)d_in[8];
  const float* dt_bias = (const float*)d_in[9];
  const float* qcw     = (const float*)d_in[10];
  const float* kcw     = (const float*)d_in[11];
  const float* vcw     = (const float*)d_in[12];

  // Workspace (63.11 MB, same proven footprint):
  //  qkv_pre [0 .. 6291456)      f32; later o[0..3145728) + goh/gol
  //  g_pre   [6291456 .. 9437184) f32; transiently holds wcat_hi before g GEMM
  //  Cu      [9437184 .. 15728640): phase1 xh,xl + wcat_lo / wg hi,lo
  //                                 phase2 qc,kc,vc ; phase3 wout hi,lo
  //  alpha/beta [15728640 .. 15777792)
  float* ws      = (float*)d_ws;
  float* qkv_pre = ws;
  float* g_pre   = ws + 6291456;
  float* Cu      = ws + 9437184;
  float* alphab  = ws + 15728640;
  float* betab   = ws + 15753216;

  ushort* xh    = (ushort*)Cu;                  // 3,145,728 ushorts
  ushort* xl    = (ushort*)(Cu + 1572864);
  ushort* wcath = (ushort*)g_pre;               // 4,718,592 ushorts (transient)
  ushort* wcatl = (ushort*)(Cu + 3145728);      // 4,718,592 ushorts
  ushort* wgh   = (ushort*)(Cu + 3145728);      // reuses wcatl space after qkv GEMM
  ushort* wgl   = (ushort*)(Cu + 4325376);

  float* qc = Cu;
  float* kc = Cu + 1572864;
  float* vc = Cu + 3145728;

  ushort* wouth = (ushort*)Cu;
  ushort* woutl = (ushort*)(Cu + 1179648);

  float*  o   = qkv_pre;
  ushort* goh = (ushort*)(qkv_pre + 3145728);
  ushort* gol = (ushort*)(qkv_pre + 4718592);

  const int M = BB * TT;  // 2048
  dim3 blk(256);

  // 1) split-casts: x, concatenated q|k|v weights
  cast_pair_kernel<<<1536, blk, 0, stream>>>(x, xh, xl);
  cast_qkv_kernel<<<2304, blk, 0, stream>>>(w_q, w_k, w_v, wcath, wcatl);

  // 2) fused qkv projection (N=3072)
  gemm_bf16s<<<dim3(CQKV / 128, M / 128), blk, 0, stream>>>(xh, xl, wcath, wcatl, qkv_pre, M, CQKV, DD, CQKV);

  // 3) g projection (wcat dead; wg overwrites wcatl, g_pre overwrites wcath)
  cast_pair_kernel<<<1152, blk, 0, stream>>>(w_g, wgh, wgl);
  gemm_bf16s<<<dim3(TVv / 128, M / 128), blk, 0, stream>>>(xh, xl, wgh, wgl, g_pre, M, TVv, DD, TVv);

  // 4) gating coefficients (f32, exact)
  gate_kernel<<<M, blk, 0, stream>>>(x, w_a, w_b, A_log, dt_bias, alphab, betab);

  // 5) causal depthwise conv + SiLU (overwrites Cu with qc/kc/vc)
  conv_silu_kernel<<<(BB * TT * CQKV + 255) / 256, blk, 0, stream>>>(qkv_pre, qcw, kcw, vcw, qc, kc, vc);

  // 6) L2 normalize q,k
  l2norm64_kernel<<<6144, blk, 0, stream>>>(qc, BB * HH * TT);
  l2norm64_kernel<<<6144, blk, 0, stream>>>(kc, BB * HH * TT);

  // 7) scan (512-thr blocks, DPP reduces, LDS alpha/beta)
  scan_kernel<<<BB * HH * 4, dim3(512), 0, stream>>>(qc, kc, vc, alphab, betab, o);

  // 8) split-cast w_out into freed qc/kc space
  cast_pair_kernel<<<1152, blk, 0, stream>>>(w_out, wouth, woutl);

  // 9) RMS norm + SiLU gate -> split bf16
  rmsgate_kernel<<<6144, blk, 0, stream>>>(o, g_pre, goh, gol);

  // 10) output projection
  gemm_bf16s<<<dim3(TVv / 128, M / 128), blk, 0, stream>>>(goh, gol, wouth, woutl, (float*)d_out, M, TVv, DD, TVv);
}

// Round 7
// 417.320 us; speedup vs baseline: 1.1173x; 1.0771x over previous
//
#include <hip/hip_runtime.h>
#include <math.h>

#define BB 2
#define TT 1024
#define DD 1536
#define HH 12
#define TQK 768
#define TVv 1536
#define CQKV 3072
#define EPSF 1e-6f
#define TSC 32   // scan time-tile (per LDS buffer)

typedef __attribute__((ext_vector_type(8))) short short8v;
typedef __attribute__((ext_vector_type(4))) float f32x4;

__device__ __forceinline__ float siluf(float x) { return x / (1.f + expf(-x)); }

__device__ __forceinline__ ushort f2b(float f) {
  union { float f; uint u; } a; a.f = f;
  uint u = a.u;
  uint r = (u + 0x7fffu + ((u >> 16) & 1u)) >> 16;   // round-to-nearest-even
  return (ushort)r;
}
__device__ __forceinline__ float b2f(ushort h) {
  union { uint u; float f; } a; a.u = (uint)h << 16; return a.f;
}

// async global->LDS. dest = wave-uniform base + lane*size; src is PER-LANE.
__device__ __forceinline__ void gload16(const void* g, void* l) {
  __builtin_amdgcn_global_load_lds(
      (const __attribute__((address_space(1))) void*)g,
      (__attribute__((address_space(3))) void*)l, 16, 0, 0);
}
__device__ __forceinline__ void gload4(const void* g, void* l) {
  __builtin_amdgcn_global_load_lds(
      (const __attribute__((address_space(1))) void*)g,
      (__attribute__((address_space(3))) void*)l, 4, 0, 0);
}

// DPP add: x += lane-permuted x. Pure VALU (no DS pipe).
// 0xB1=quad_perm xor1, 0x4E=quad_perm xor2, 0x141=row_half_mirror,
// 0x140=row_mirror. All stay inside a 16-lane row.
template <int CTRL>
__device__ __forceinline__ float dpp_xadd(float x) {
  union { float f; int i; } a, b;
  a.f = x;
  b.i = __builtin_amdgcn_update_dpp(0, a.i, CTRL, 0xF, 0xF, true);
  return x + b.f;
}
__device__ __forceinline__ float red16_dpp(float x) {
  x = dpp_xadd<0xB1>(x);
  x = dpp_xadd<0x4E>(x);
  x = dpp_xadd<0x141>(x);
  x = dpp_xadd<0x140>(x);
  return x;
}

// ---------------------------------------------------------------------------
// Split-bf16 MFMA GEMM (unchanged from R6, passing): C = X @ W^T via
// Xl*Wh + Xh*Wl + Xh*Wh; 128x128 tile, BK=64, global_load_lds staging with
// XOR-swizzled source + swizzled ds_read.
// ---------------------------------------------------------------------------
__global__ __launch_bounds__(256) void gemm_bf16s(
    const ushort* __restrict__ Xh, const ushort* __restrict__ Xl,
    const ushort* __restrict__ Wh, const ushort* __restrict__ Wl,
    float* __restrict__ C, int M, int N, int K, int ldc)
{
  __shared__ ushort Ah[128 * 64];
  __shared__ ushort Al[128 * 64];
  __shared__ ushort Bh[128 * 64];
  __shared__ ushort Bl[128 * 64];
  const int tid  = threadIdx.x;
  const int lane = tid & 63;
  const int w    = tid >> 6;
  const int wr   = w >> 1, wc = w & 1;
  const int r0   = blockIdx.y * 128, c0 = blockIdx.x * 128;

  const int dr   = lane >> 3;
  const int slot = (lane & 7) ^ dr;

  f32x4 acc[4][4];
#pragma unroll
  for (int m = 0; m < 4; ++m)
#pragma unroll
    for (int n = 0; n < 4; ++n)
#pragma unroll
      for (int j = 0; j < 4; ++j) acc[m][n][j] = 0.f;

  for (int k0 = 0; k0 < K; k0 += 64) {
#pragma unroll
    for (int j = 0; j < 4; ++j) {
      const int row  = (w * 4 + j) * 8 + dr;
      const size_t xo = (size_t)(r0 + row) * K + k0 + slot * 8;
      const size_t wo = (size_t)(c0 + row) * K + k0 + slot * 8;
      const int ldso = (w * 4 + j) * 512;
      gload16(Xh + xo, Ah + ldso);
      gload16(Xl + xo, Al + ldso);
      gload16(Wh + wo, Bh + ldso);
      gload16(Wl + wo, Bl + ldso);
    }
    __syncthreads();
#pragma unroll
    for (int kk = 0; kk < 2; ++kk) {
      const int kc8 = kk * 4 + (lane >> 4);
      const int sw  = (kc8 ^ (lane & 7)) << 3;
      short8v ah[4], al_[4], bh[4], bl[4];
#pragma unroll
      for (int m = 0; m < 4; ++m) {
        const int ro = (wr * 64 + m * 16 + (lane & 15)) * 64 + sw;
        ah[m]  = *(const short8v*)(Ah + ro);
        al_[m] = *(const short8v*)(Al + ro);
      }
#pragma unroll
      for (int n = 0; n < 4; ++n) {
        const int ro = (wc * 64 + n * 16 + (lane & 15)) * 64 + sw;
        bh[n] = *(const short8v*)(Bh + ro);
        bl[n] = *(const short8v*)(Bl + ro);
      }
#pragma unroll
      for (int m = 0; m < 4; ++m)
#pragma unroll
        for (int n = 0; n < 4; ++n) {
          acc[m][n] = __builtin_amdgcn_mfma_f32_16x16x32_bf16(al_[m], bh[n], acc[m][n], 0, 0, 0);
          acc[m][n] = __builtin_amdgcn_mfma_f32_16x16x32_bf16(ah[m], bl[n], acc[m][n], 0, 0, 0);
          acc[m][n] = __builtin_amdgcn_mfma_f32_16x16x32_bf16(ah[m], bh[n], acc[m][n], 0, 0, 0);
        }
    }
    __syncthreads();
  }

  const int crow = (lane >> 4) * 4;
  const int ccol = lane & 15;
#pragma unroll
  for (int m = 0; m < 4; ++m)
#pragma unroll
    for (int j = 0; j < 4; ++j) {
      float* cp = C + (size_t)(r0 + wr * 64 + m * 16 + crow + j) * ldc + c0 + wc * 64 + ccol;
#pragma unroll
      for (int n = 0; n < 4; ++n) cp[n * 16] = acc[m][n][j];
    }
}

// ---------------------------------------------------------------------------
// f32 -> (bf16 hi, bf16 lo) split casts.
// ---------------------------------------------------------------------------
__device__ __forceinline__ void split8_store(const float* f, ushort* hi, ushort* lo, size_t e)
{
  ushort h[8], l[8];
#pragma unroll
  for (int j = 0; j < 8; ++j) {
    h[j] = f2b(f[j]);
    l[j] = f2b(f[j] - b2f(h[j]));
  }
  uint4 ph, pl;
  ph.x = (uint)h[0] | ((uint)h[1] << 16); ph.y = (uint)h[2] | ((uint)h[3] << 16);
  ph.z = (uint)h[4] | ((uint)h[5] << 16); ph.w = (uint)h[6] | ((uint)h[7] << 16);
  pl.x = (uint)l[0] | ((uint)l[1] << 16); pl.y = (uint)l[2] | ((uint)l[3] << 16);
  pl.z = (uint)l[4] | ((uint)l[5] << 16); pl.w = (uint)l[6] | ((uint)l[7] << 16);
  *(uint4*)(hi + e) = ph;
  *(uint4*)(lo + e) = pl;
}

__global__ void cast_pair_kernel(const float* __restrict__ src,
                                 ushort* __restrict__ hi, ushort* __restrict__ lo)
{
  int cid = blockIdx.x * blockDim.x + threadIdx.x;
  size_t e = (size_t)cid * 8;
  float f[8];
  *(float4*)(f)     = *(const float4*)(src + e);
  *(float4*)(f + 4) = *(const float4*)(src + e + 4);
  split8_store(f, hi, lo, e);
}

__global__ void cast_qkv_kernel(const float* __restrict__ wq, const float* __restrict__ wk,
                                const float* __restrict__ wv,
                                ushort* __restrict__ hi, ushort* __restrict__ lo)
{
  int cid = blockIdx.x * blockDim.x + threadIdx.x;
  size_t e = (size_t)cid * 8;
  const float* src; size_t off;
  if (e < 1179648)      { src = wq; off = e; }
  else if (e < 2359296) { src = wk; off = e - 1179648; }
  else                  { src = wv; off = e - 2359296; }
  float f[8];
  *(float4*)(f)     = *(const float4*)(src + off);
  *(float4*)(f + 4) = *(const float4*)(src + off + 4);
  split8_store(f, hi, lo, e);
}

// ---------------------------------------------------------------------------
// Causal depthwise conv (K=4) + SiLU; writes q/k/v transposed to (B,H,T,D).
// ---------------------------------------------------------------------------
__global__ void conv_silu_kernel(
    const float* __restrict__ pre,
    const float* __restrict__ qw, const float* __restrict__ kw, const float* __restrict__ vw,
    float* __restrict__ qc, float* __restrict__ kc, float* __restrict__ vc)
{
  int idx = blockIdx.x * blockDim.x + threadIdx.x;
  if (idx >= BB * TT * CQKV) return;
  int c  = idx % CQKV;
  int bt = idx / CQKV;
  int t  = bt % TT;
  int b  = bt / TT;

  const float* wp;
  if (c < TQK)          wp = qw + (size_t)c * 4;
  else if (c < 2 * TQK) wp = kw + (size_t)(c - TQK) * 4;
  else                  wp = vw + (size_t)(c - 2 * TQK) * 4;

  float s = 0.f;
#pragma unroll
  for (int j = 0; j < 4; ++j) {
    int ts = t - 3 + j;
    if (ts >= 0) s = fmaf(pre[(size_t)(b * TT + ts) * CQKV + c], wp[j], s);
  }
  s = siluf(s);

  if (c < TQK) {
    int h = c >> 6, d = c & 63;
    qc[((size_t)(b * HH + h) * TT + t) * 64 + d] = s;
  } else if (c < 2 * TQK) {
    int c2 = c - TQK; int h = c2 >> 6, d = c2 & 63;
    kc[((size_t)(b * HH + h) * TT + t) * 64 + d] = s;
  } else {
    int c2 = c - 2 * TQK; int h = c2 >> 7, d = c2 & 127;
    vc[((size_t)(b * HH + h) * TT + t) * 128 + d] = s;
  }
}

__global__ void l2norm64_kernel(float* __restrict__ buf, int nrows)
{
  int gid  = blockIdx.x * blockDim.x + threadIdx.x;
  int row  = gid >> 6;
  int lane = threadIdx.x & 63;
  if (row >= nrows) return;
  float v = buf[(size_t)row * 64 + lane];
  float ss = v * v;
#pragma unroll
  for (int m = 32; m >= 1; m >>= 1) ss += __shfl_xor(ss, m, 64);
  float n = sqrtf(ss);
  buf[(size_t)row * 64 + lane] = v / fmaxf(n, EPSF);
}

// ---------------------------------------------------------------------------
// Gating: one block per row m; 4 waves x 6 outputs.
// ---------------------------------------------------------------------------
__global__ __launch_bounds__(256) void gate_kernel(
    const float* __restrict__ x, const float* __restrict__ w_a, const float* __restrict__ w_b,
    const float* __restrict__ A_log, const float* __restrict__ dt_bias,
    float* __restrict__ alpha, float* __restrict__ beta)
{
  const int m    = blockIdx.x;
  const int w    = threadIdx.x >> 6;
  const int lane = threadIdx.x & 63;
  const float* xr = x + (size_t)m * DD;
  float xv[24];
#pragma unroll
  for (int i = 0; i < 24; ++i) xv[i] = xr[lane + i * 64];
  const int b = m / TT, t = m % TT;
#pragma unroll
  for (int j = 0; j < 6; ++j) {
    int o = w * 6 + j;
    bool isA = o < HH;
    int h = isA ? o : o - HH;
    const float* wr = (isA ? w_a : w_b) + (size_t)h * DD;
    float s = 0.f;
#pragma unroll
    for (int i = 0; i < 24; ++i) s = fmaf(xv[i], wr[lane + i * 64], s);
#pragma unroll
    for (int mm = 32; mm >= 1; mm >>= 1) s += __shfl_xor(s, mm, 64);
    if (lane == 0) {
      size_t idx = (size_t)(b * HH + h) * TT + t;
      if (isA) {
        float a  = s + dt_bias[h];
        float sp = (a > 20.f) ? a : log1pf(expf(a));
        alpha[idx] = expf(-expf(A_log[h]) * sp);
      } else {
        beta[idx] = 2.f / (1.f + expf(-s));
      }
    }
  }
}

// ---------------------------------------------------------------------------
// Gated delta scan v3: 768 blocks = 32 vgroups x 24 bh, ONE wave each.
// blk = vg*24 + bh  ->  all 32 same-bh blocks land on XCD bh%8 (L2 dedupes
// the broadcast k/q reads). Lane = (cp, s): cp=tid>>4 owns col vg*4+cp,
// s=tid&15 owns d = s*4..s*4+3. Staging: 19 global_load_lds per 32-step tile
// (8 k + 8 q + 2 v-gather + 1 ab-gather), double-buffered, counted
// s_waitcnt vmcnt(19) so next-tile loads fly during compute. Reduces: DPP.
// ---------------------------------------------------------------------------
__global__ __launch_bounds__(64) void scan_kernel(
    const float* __restrict__ qc, const float* __restrict__ kc, const float* __restrict__ vc,
    const float* __restrict__ alpha, const float* __restrict__ beta,
    float* __restrict__ o)
{
  __shared__ float k_lds[2][TSC * 64];
  __shared__ float q_lds[2][TSC * 64];
  __shared__ float v_lds[2][TSC * 4];
  __shared__ float ab_lds[2][TSC * 2];

  const int blk  = blockIdx.x;
  const int bh   = blk % 24;          // XCD affinity: bh%8
  const int vg   = blk / 24;          // 0..31
  const int b    = bh / HH, h = bh % HH;
  const int lane = threadIdx.x;       // 0..63
  const int cp   = lane >> 4;         // 0..3
  const int s    = lane & 15;         // 0..15, owns d = s*4..s*4+3

  const float* kg = kc + (size_t)bh * TT * 64;
  const float* qg = qc + (size_t)bh * TT * 64;
  const float* ag = alpha + (size_t)bh * TT;
  const float* bg = beta  + (size_t)bh * TT;

  // per-lane gather sources
  const float* vsrc = vc + (size_t)bh * TT * 128 + (size_t)(lane >> 2) * 128 + vg * 4 + (lane & 3);
  const float* absrc = ((lane & 1) ? bg : ag) + (lane >> 1);

  float* op = o + ((size_t)b * TT * HH + h) * 128 + vg * 4 + cp;

#define STAGE(B, T0) do { \
    _Pragma("unroll") \
    for (int j = 0; j < 8; ++j) { \
      gload16(kg + (size_t)((T0) + 4 * j) * 64 + lane * 4, &k_lds[B][j * 256]); \
      gload16(qg + (size_t)((T0) + 4 * j) * 64 + lane * 4, &q_lds[B][j * 256]); \
    } \
    gload4(vsrc + (size_t)(T0) * 128,        &v_lds[B][0]);  \
    gload4(vsrc + (size_t)((T0) + 16) * 128, &v_lds[B][64]); \
    gload4(absrc + (T0), &ab_lds[B][0]); \
  } while (0)

  float S[4];
#pragma unroll
  for (int i = 0; i < 4; ++i) S[i] = 0.f;

  STAGE(0, 0);
  for (int tile = 0; tile < TT / TSC; ++tile) {
    const int cur = tile & 1;
    if (tile + 1 < TT / TSC) {
      STAGE(cur ^ 1, (tile + 1) * TSC);
      asm volatile("s_waitcnt vmcnt(19)" ::: "memory");
    } else {
      asm volatile("s_waitcnt vmcnt(0)" ::: "memory");
    }
    __builtin_amdgcn_sched_barrier(0);

#pragma unroll 8
    for (int i = 0; i < TSC; ++i) {
      const float4 kk = *(const float4*)(&k_lds[cur][i * 64 + s * 4]);
      const float4 qq = *(const float4*)(&q_lds[cur][i * 64 + s * 4]);
      const float vt = v_lds[cur][i * 4 + cp];
      const float2 ab = *(const float2*)(&ab_lds[cur][2 * i]);
      const float al = ab.x, be = ab.y;

      float pa = fmaf(kk.y, S[1], kk.x * S[0]);
      float pb = fmaf(kk.w, S[3], kk.z * S[2]);
      float sa = fmaf(qq.y, S[1], qq.x * S[0]);
      float sb = fmaf(qq.w, S[3], qq.z * S[2]);
      float ta = fmaf(qq.y, kk.y, qq.x * kk.x);
      float tb = fmaf(qq.w, kk.w, qq.z * kk.z);

      float part = red16_dpp(pa + pb);   // k.S (serial chain, pure VALU)
      float qs   = red16_dpp(sa + sb);   // q.S (off-chain)
      float qk   = red16_dpp(ta + tb);   // q.k (off-chain)
      const float c = fmaf(-al * be, part, vt);
      S[0] = fmaf(al, S[0], c * kk.x);
      S[1] = fmaf(al, S[1], c * kk.y);
      S[2] = fmaf(al, S[2], c * kk.z);
      S[3] = fmaf(al, S[3], c * kk.w);
      if (s == 0) *op = fmaf(al, qs, c * qk);
      op += HH * 128;
    }
  }
#undef STAGE
}

// ---------------------------------------------------------------------------
// RMS norm over 128 + SiLU gate; emits split bf16 (hi+lo) for final GEMM.
// ---------------------------------------------------------------------------
__global__ void rmsgate_kernel(const float* __restrict__ o, const float* __restrict__ gpre,
                               ushort* __restrict__ goh, ushort* __restrict__ gol)
{
  int gid  = blockIdx.x * blockDim.x + threadIdx.x;
  int wid  = gid >> 6;
  int lane = threadIdx.x & 63;
  if (wid >= BB * TT * HH) return;
  int h = wid % HH;
  int m = wid / HH;
  const float* orow = o + (size_t)wid * 128;
  float2 ov = *(const float2*)(orow + lane * 2);
  float ss = ov.x * ov.x + ov.y * ov.y;
#pragma unroll
  for (int mm = 32; mm >= 1; mm >>= 1) ss += __shfl_xor(ss, mm, 64);
  float scale = rsqrtf(ss * (1.f / 128.f) + EPSF);
  const float* gr = gpre + (size_t)m * TVv + h * 128 + lane * 2;
  float o0 = ov.x * scale * siluf(gr[0]);
  float o1 = ov.y * scale * siluf(gr[1]);
  ushort h0 = f2b(o0), h1 = f2b(o1);
  ushort l0 = f2b(o0 - b2f(h0)), l1 = f2b(o1 - b2f(h1));
  size_t idx = (size_t)m * TVv + h * 128 + lane * 2;
  *(uint*)(goh + idx) = (uint)h0 | ((uint)h1 << 16);
  *(uint*)(gol + idx) = (uint)l0 | ((uint)l1 << 16);
}

// ---------------------------------------------------------------------------
extern "C" void kernel_launch(void* const* d_in, const int* in_sizes, int n_in,
                              void* d_out, int out_size, void* d_ws, size_t ws_size,
                              hipStream_t stream) {
  (void)in_sizes; (void)n_in; (void)out_size; (void)ws_size;
  const float* x       = (const float*)d_in[0];
  const float* w_q     = (const float*)d_in[1];
  const float* w_k     = (const float*)d_in[2];
  const float* w_v     = (const float*)d_in[3];
  const float* w_a     = (const float*)d_in[4];
  const float* w_b     = (const float*)d_in[5];
  const float* w_g     = (const float*)d_in[6];
  const float* w_out   = (const float*)d_in[7];
  const float* A_log   = (const float*)d_in[8];
  const float* dt_bias = (const float*)d_in[9];
  const float* qcw     = (const float*)d_in[10];
  const float* kcw     = (const float*)d_in[11];
  const float* vcw     = (const float*)d_in[12];

  // Workspace (63.11 MB, same proven footprint).
  float* ws      = (float*)d_ws;
  float* qkv_pre = ws;
  float* g_pre   = ws + 6291456;
  float* Cu      = ws + 9437184;
  float* alphab  = ws + 15728640;
  float* betab   = ws + 15753216;

  ushort* xh    = (ushort*)Cu;
  ushort* xl    = (ushort*)(Cu + 1572864);
  ushort* wcath = (ushort*)g_pre;
  ushort* wcatl = (ushort*)(Cu + 3145728);
  ushort* wgh   = (ushort*)(Cu + 3145728);
  ushort* wgl   = (ushort*)(Cu + 4325376);

  float* qc = Cu;
  float* kc = Cu + 1572864;
  float* vc = Cu + 3145728;

  ushort* wouth = (ushort*)Cu;
  ushort* woutl = (ushort*)(Cu + 1179648);

  float*  o   = qkv_pre;
  ushort* goh = (ushort*)(qkv_pre + 3145728);
  ushort* gol = (ushort*)(qkv_pre + 4718592);

  const int M = BB * TT;  // 2048
  dim3 blk(256);

  // 1) split-casts: x, concatenated q|k|v weights
  cast_pair_kernel<<<1536, blk, 0, stream>>>(x, xh, xl);
  cast_qkv_kernel<<<2304, blk, 0, stream>>>(w_q, w_k, w_v, wcath, wcatl);

  // 2) fused qkv projection (N=3072)
  gemm_bf16s<<<dim3(CQKV / 128, M / 128), blk, 0, stream>>>(xh, xl, wcath, wcatl, qkv_pre, M, CQKV, DD, CQKV);

  // 3) g projection
  cast_pair_kernel<<<1152, blk, 0, stream>>>(w_g, wgh, wgl);
  gemm_bf16s<<<dim3(TVv / 128, M / 128), blk, 0, stream>>>(xh, xl, wgh, wgl, g_pre, M, TVv, DD, TVv);

  // 4) gating coefficients (f32, exact)
  gate_kernel<<<M, blk, 0, stream>>>(x, w_a, w_b, A_log, dt_bias, alphab, betab);

  // 5) causal depthwise conv + SiLU
  conv_silu_kernel<<<(BB * TT * CQKV + 255) / 256, blk, 0, stream>>>(qkv_pre, qcw, kcw, vcw, qc, kc, vc);

  // 6) L2 normalize q,k
  l2norm64_kernel<<<6144, blk, 0, stream>>>(qc, BB * HH * TT);
  l2norm64_kernel<<<6144, blk, 0, stream>>>(kc, BB * HH * TT);

  // 7) scan v3: 768 one-wave blocks, XCD-affine by bh
  scan_kernel<<<768, dim3(64), 0, stream>>>(qc, kc, vc, alphab, betab, o);

  // 8) split-cast w_out
  cast_pair_kernel<<<1152, blk, 0, stream>>>(w_out, wouth, woutl);

  // 9) RMS norm + SiLU gate -> split bf16
  rmsgate_kernel<<<6144, blk, 0, stream>>>(o, g_pre, goh, gol);

  // 10) output projection
  gemm_bf16s<<<dim3(TVv / 128, M / 128), blk, 0, stream>>>(goh, gol, wouth, woutl, (float*)d_out, M, TVv, DD, TVv);
}